// Round 1
// baseline (437.473 us; speedup 1.0000x reference)
//
#include <hip/hip_runtime.h>
#include <math.h>

#define N_IN_CH 256
#define N_OUT   256   // HEADS * OUT_CH
#define HEADS   4
#define OUT_CH  64
#define NT      32    // nodes per block in proj kernel
#define SCAN_BLOCK 1024

__device__ __forceinline__ float lrelu(float a) {
  return a >= 0.f ? a : 0.2f * a;
}

// ---------------- Kernel A: x_h = x @ W'  + attention logits ----------------
__global__ __launch_bounds__(256) void proj_kernel(
    const float* __restrict__ x, const float* __restrict__ weight,
    const float* __restrict__ att_src, const float* __restrict__ att_dst,
    float* __restrict__ xh, float* __restrict__ asrc, float* __restrict__ adst,
    int nnodes) {
  __shared__ float xt[NT * N_IN_CH];  // 32 KB
  const int tid = threadIdx.x;
  const int n0 = blockIdx.x * NT;
  const int nvalid = min(NT, nnodes - n0);

  {
    const float4* src4 = (const float4*)(x + (size_t)n0 * N_IN_CH);
    float4* dst4 = (float4*)xt;
    const int tot4 = nvalid * (N_IN_CH / 4);
    for (int i = tid; i < NT * (N_IN_CH / 4); i += 256) {
      float4 v = make_float4(0.f, 0.f, 0.f, 0.f);
      if (i < tot4) v = src4[i];
      dst4[i] = v;
    }
  }
  __syncthreads();

  const int h = tid >> 6;   // wave id == head
  const int c = tid & 63;   // lane == out channel within head
  const float* Wp = weight + (size_t)h * (N_IN_CH * OUT_CH) + c;

  float acc[NT];
#pragma unroll
  for (int n = 0; n < NT; ++n) acc[n] = 0.f;

  const float4* xt4 = (const float4*)xt;
  for (int k = 0; k < N_IN_CH; k += 4) {
    const float w0 = Wp[(k + 0) * OUT_CH];
    const float w1 = Wp[(k + 1) * OUT_CH];
    const float w2 = Wp[(k + 2) * OUT_CH];
    const float w3 = Wp[(k + 3) * OUT_CH];
    const int k4 = k >> 2;
#pragma unroll
    for (int n = 0; n < NT; ++n) {
      float4 xv = xt4[n * (N_IN_CH / 4) + k4];
      float a = acc[n];
      a = fmaf(xv.x, w0, a);
      a = fmaf(xv.y, w1, a);
      a = fmaf(xv.z, w2, a);
      a = fmaf(xv.w, w3, a);
      acc[n] = a;
    }
  }

  // store x_h (coalesced: tid spans the 256 output cols)
  for (int n = 0; n < nvalid; ++n) {
    xh[(size_t)(n0 + n) * N_OUT + tid] = acc[n];
  }

  // fused attention logits: alpha_src[n,h] = sum_c x_h[n,h,c]*att_src[h,c]
  const float atts = att_src[h * OUT_CH + c];
  const float attd = att_dst[h * OUT_CH + c];
  for (int n = 0; n < NT; ++n) {
    float vs = acc[n] * atts;
    float vd = acc[n] * attd;
#pragma unroll
    for (int d = 1; d < 64; d <<= 1) {
      vs += __shfl_xor(vs, d, 64);
      vd += __shfl_xor(vd, d, 64);
    }
    if (c == 0 && n < nvalid) {
      asrc[(n0 + n) * HEADS + h] = vs;
      adst[(n0 + n) * HEADS + h] = vd;
    }
  }
}

// ---------------- Kernel B: count edges per destination (row) ----------------
__global__ void count_kernel(const int* __restrict__ row, int* __restrict__ counts,
                             int nedges) {
  int e = blockIdx.x * blockDim.x + threadIdx.x;
  if (e < nedges) atomicAdd(&counts[row[e]], 1);
}

// ---------------- Scan (3 tiny kernels, hierarchical) ----------------
__global__ __launch_bounds__(SCAN_BLOCK) void scan1_kernel(
    const int* __restrict__ counts, int* __restrict__ offsets,
    int* __restrict__ partials, int n) {
  __shared__ int wsum[16];
  const int tid = threadIdx.x;
  const int lane = tid & 63;
  const int wid = tid >> 6;
  const int i = blockIdx.x * SCAN_BLOCK + tid;
  int v = (i < n) ? counts[i] : 0;
  int incl = v;
#pragma unroll
  for (int d = 1; d < 64; d <<= 1) {
    int t = __shfl_up(incl, d, 64);
    if (lane >= d) incl += t;
  }
  if (lane == 63) wsum[wid] = incl;
  __syncthreads();
  if (wid == 0) {
    int wv = (lane < 16) ? wsum[lane] : 0;
#pragma unroll
    for (int d = 1; d < 16; d <<= 1) {
      int t = __shfl_up(wv, d, 64);
      if (lane >= d) wv += t;
    }
    if (lane < 16) wsum[lane] = wv;
  }
  __syncthreads();
  const int wexcl = (wid == 0) ? 0 : wsum[wid - 1];
  if (i < n) offsets[i] = wexcl + incl - v;
  if (tid == SCAN_BLOCK - 1) partials[blockIdx.x] = wsum[15];
}

__global__ void scan2_kernel(int* __restrict__ partials, int* __restrict__ offsets,
                             int nparts, int n) {
  const int lane = threadIdx.x;  // 64 threads, nparts <= 64
  int v = (lane < nparts) ? partials[lane] : 0;
  int incl = v;
#pragma unroll
  for (int d = 1; d < 64; d <<= 1) {
    int t = __shfl_up(incl, d, 64);
    if (lane >= d) incl += t;
  }
  if (lane < nparts) partials[lane] = incl - v;  // exclusive
  if (lane == 63) offsets[n] = incl;             // grand total
}

__global__ __launch_bounds__(SCAN_BLOCK) void scan3_kernel(
    int* __restrict__ offsets, const int* __restrict__ partials, int n) {
  const int i = blockIdx.x * SCAN_BLOCK + threadIdx.x;
  if (i < n) offsets[i] += partials[blockIdx.x];
}

// ---------------- Kernel D: scatter edge ids into CSR ----------------
__global__ void scatter_kernel(const int* __restrict__ row, const int* __restrict__ offsets,
                               int* __restrict__ cursor, int* __restrict__ elist,
                               int nedges) {
  int e = blockIdx.x * blockDim.x + threadIdx.x;
  if (e < nedges) {
    int r = row[e];
    int pos = offsets[r] + atomicAdd(&cursor[r], 1);
    elist[pos] = e;
  }
}

// ---------------- Kernel E: per-node softmax + weighted gather ----------------
__global__ __launch_bounds__(256) void gather_kernel(
    const int* __restrict__ offsets, const int* __restrict__ elist,
    const int* __restrict__ col, const float* __restrict__ asrc,
    const float* __restrict__ adst, const float* __restrict__ xh,
    const float* __restrict__ bias, float* __restrict__ out, int nnodes) {
  const int n = blockIdx.x * 4 + (threadIdx.x >> 6);  // one wave per node
  const int lane = threadIdx.x & 63;
  if (n >= nnodes) return;
  const int off = offsets[n];
  const int deg = offsets[n + 1] - off;
  const int h = lane >> 4;  // lane owns channels [4*lane, 4*lane+4) -> head lane>>4

  const float4 as4 = *(const float4*)&asrc[n * 4];

  // phase 1: per-head max over this node's edges
  float m0 = -1e30f, m1 = -1e30f, m2 = -1e30f, m3 = -1e30f;
  for (int i = lane; i < deg; i += 64) {
    const int e = elist[off + i];
    const int cl = col[e];
    const float4 ad = *(const float4*)&adst[cl * 4];
    m0 = fmaxf(m0, lrelu(as4.x + ad.x));
    m1 = fmaxf(m1, lrelu(as4.y + ad.y));
    m2 = fmaxf(m2, lrelu(as4.z + ad.z));
    m3 = fmaxf(m3, lrelu(as4.w + ad.w));
  }
#pragma unroll
  for (int d = 1; d < 64; d <<= 1) {
    m0 = fmaxf(m0, __shfl_xor(m0, d, 64));
    m1 = fmaxf(m1, __shfl_xor(m1, d, 64));
    m2 = fmaxf(m2, __shfl_xor(m2, d, 64));
    m3 = fmaxf(m3, __shfl_xor(m3, d, 64));
  }

  // phase 2: per-head sum of exp(alpha - max)
  float s0 = 0.f, s1 = 0.f, s2 = 0.f, s3 = 0.f;
  for (int i = lane; i < deg; i += 64) {
    const int e = elist[off + i];
    const int cl = col[e];
    const float4 ad = *(const float4*)&adst[cl * 4];
    s0 += __expf(lrelu(as4.x + ad.x) - m0);
    s1 += __expf(lrelu(as4.y + ad.y) - m1);
    s2 += __expf(lrelu(as4.z + ad.z) - m2);
    s3 += __expf(lrelu(as4.w + ad.w) - m3);
  }
#pragma unroll
  for (int d = 1; d < 64; d <<= 1) {
    s0 += __shfl_xor(s0, d, 64);
    s1 += __shfl_xor(s1, d, 64);
    s2 += __shfl_xor(s2, d, 64);
    s3 += __shfl_xor(s3, d, 64);
  }

  const float mh   = (h == 0) ? m0 : (h == 1) ? m1 : (h == 2) ? m2 : m3;
  const float sh   = (h == 0) ? s0 : (h == 1) ? s1 : (h == 2) ? s2 : s3;
  const float ash  = (h == 0) ? as4.x : (h == 1) ? as4.y : (h == 2) ? as4.z : as4.w;
  const float invh = 1.f / fmaxf(sh, 1e-16f);

  // phase 3: weighted gather-accumulate of x_h[col] rows
  float4 acc = make_float4(0.f, 0.f, 0.f, 0.f);
  for (int i = 0; i < deg; ++i) {
    const int e = elist[off + i];        // wave-uniform
    const int cl = col[e];
    const float ad = adst[cl * 4 + h];
    const float w = __expf(lrelu(ash + ad) - mh) * invh;
    const float4 xv = *(const float4*)&xh[(size_t)cl * N_OUT + (lane << 2)];
    acc.x = fmaf(w, xv.x, acc.x);
    acc.y = fmaf(w, xv.y, acc.y);
    acc.z = fmaf(w, xv.z, acc.z);
    acc.w = fmaf(w, xv.w, acc.w);
  }

  const float4 b4 = *(const float4*)&bias[lane << 2];
  float4 o = make_float4(acc.x + b4.x, acc.y + b4.y, acc.z + b4.z, acc.w + b4.w);
  *(float4*)&out[(size_t)n * N_OUT + (lane << 2)] = o;
}

extern "C" void kernel_launch(void* const* d_in, const int* in_sizes, int n_in,
                              void* d_out, int out_size, void* d_ws, size_t ws_size,
                              hipStream_t stream) {
  const float* x        = (const float*)d_in[0];
  const int*   edge_idx = (const int*)d_in[1];
  const float* weight   = (const float*)d_in[2];
  const float* att_src  = (const float*)d_in[3];
  const float* att_dst  = (const float*)d_in[4];
  const float* bias     = (const float*)d_in[5];
  float* out = (float*)d_out;

  const int nnodes = in_sizes[0] / N_IN_CH;
  const int nedges = in_sizes[1] / 2;
  const int* row = edge_idx;            // destinations (segment index)
  const int* col = edge_idx + nedges;   // sources (features gathered)

  // workspace carve-up (256B aligned): ~56.6 MB total
  char* wsb = (char*)d_ws;
  size_t woff = 0;
  auto alloc = [&](size_t bytes) -> char* {
    char* p = wsb + woff;
    woff += (bytes + 255) & ~(size_t)255;
    return p;
  };
  float* xh     = (float*)alloc((size_t)nnodes * N_OUT * sizeof(float));
  float* asrc   = (float*)alloc((size_t)nnodes * HEADS * sizeof(float));
  float* adst   = (float*)alloc((size_t)nnodes * HEADS * sizeof(float));
  int* counts   = (int*)alloc((size_t)nnodes * sizeof(int));
  int* cursor   = (int*)alloc((size_t)nnodes * sizeof(int));
  int* offsets  = (int*)alloc((size_t)(nnodes + 1) * sizeof(int));
  int* partials = (int*)alloc(256 * sizeof(int));
  int* elist    = (int*)alloc((size_t)nedges * sizeof(int));

  hipMemsetAsync(counts, 0, (size_t)nnodes * sizeof(int), stream);
  hipMemsetAsync(cursor, 0, (size_t)nnodes * sizeof(int), stream);

  const int nblocksA = (nnodes + NT - 1) / NT;
  proj_kernel<<<nblocksA, 256, 0, stream>>>(x, weight, att_src, att_dst,
                                            xh, asrc, adst, nnodes);

  const int eblocks = (nedges + 255) / 256;
  count_kernel<<<eblocks, 256, 0, stream>>>(row, counts, nedges);

  const int nscan = (nnodes + SCAN_BLOCK - 1) / SCAN_BLOCK;  // 49 <= 64
  scan1_kernel<<<nscan, SCAN_BLOCK, 0, stream>>>(counts, offsets, partials, nnodes);
  scan2_kernel<<<1, 64, 0, stream>>>(partials, offsets, nscan, nnodes);
  scan3_kernel<<<nscan, SCAN_BLOCK, 0, stream>>>(offsets, partials, nnodes);

  scatter_kernel<<<eblocks, 256, 0, stream>>>(row, offsets, cursor, elist, nedges);

  gather_kernel<<<(nnodes + 3) / 4, 256, 0, stream>>>(offsets, elist, col, asrc, adst,
                                                      xh, bias, out, nnodes);
}

// Round 2
// 286.453 us; speedup vs baseline: 1.5272x; 1.5272x over previous
//
#include <hip/hip_runtime.h>
#include <math.h>

#define N_IN_CH 256
#define N_OUT   256   // HEADS * OUT_CH
#define HEADS   4
#define OUT_CH  64
#define BM      64    // M-tile (nodes) per block in MFMA proj kernel
#define SCAN_BLOCK 1024

typedef __attribute__((ext_vector_type(8))) short bf16x8;
typedef __attribute__((ext_vector_type(4))) float f32x4;

__device__ __forceinline__ float lrelu(float a) {
  return a >= 0.f ? a : 0.2f * a;
}

__device__ __forceinline__ ushort f2bf(float f) {
  uint u = __float_as_uint(f);
  uint r = (u + 0x7FFFu + ((u >> 16) & 1u)) >> 16;
  return (ushort)r;
}

// -------- Kernel W: weight [H][K][C] fp32 -> Bt [N=h*64+c][K] bf16 --------
__global__ void convert_w(const float* __restrict__ w, ushort* __restrict__ bt) {
  const int idx = blockIdx.x * 256 + threadIdx.x;  // 0..65535
  const int n = idx >> 8, k = idx & 255;
  const int h = n >> 6, c = n & 63;
  bt[idx] = f2bf(w[h * (N_IN_CH * OUT_CH) + k * OUT_CH + c]);
}

// -------- Kernel A: x_h = x @ W' via MFMA + fused attention logits --------
// block = 256 threads = 4 waves; block tile 64(M) x 256(N); wave w owns head w.
__global__ __launch_bounds__(256) void proj_mfma(
    const float* __restrict__ x, const ushort* __restrict__ bt,
    const float* __restrict__ att_src, const float* __restrict__ att_dst,
    ushort* __restrict__ xh, float* __restrict__ asrc, float* __restrict__ adst,
    int nnodes) {
  __shared__ ushort at[BM * N_IN_CH];  // 32 KB, XOR-swizzled rows of A (bf16)
  const int tid = threadIdx.x;
  const int wave = tid >> 6;
  const int lane = tid & 63;
  const int n0 = blockIdx.x * BM;

  // ---- stage A: fp32 -> bf16, swizzled LDS write (conflict-free) ----
  {
    const int rsub = tid >> 6;        // 0..3 (row within iteration group)
    const int cf = (tid & 63) * 4;    // float col 0..252
    const int cb = cf * 2;            // byte col in bf16 row (8-aligned)
#pragma unroll
    for (int it = 0; it < 16; ++it) {
      const int row = it * 4 + rsub;
      const int grow = n0 + row;
      float4 xv = make_float4(0.f, 0.f, 0.f, 0.f);
      if (grow < nnodes) xv = *(const float4*)&x[(size_t)grow * N_IN_CH + cf];
      ushort4 b;
      b.x = f2bf(xv.x); b.y = f2bf(xv.y); b.z = f2bf(xv.z); b.w = f2bf(xv.w);
      const int cbs = cb ^ ((row & 7) << 4);
      *(ushort4*)((char*)at + row * 512 + cbs) = b;
    }
  }
  __syncthreads();

  // ---- MFMA main loop: K=256 in 8 steps of 32 ----
  f32x4 acc[4][4];
#pragma unroll
  for (int mt = 0; mt < 4; ++mt)
#pragma unroll
    for (int nt = 0; nt < 4; ++nt) acc[mt][nt] = (f32x4){0.f, 0.f, 0.f, 0.f};

  const int lmod = lane & 15;
  const int ldiv = lane >> 4;

  for (int ks = 0; ks < 8; ++ks) {
    bf16x8 a[4], b[4];
#pragma unroll
    for (int mt = 0; mt < 4; ++mt) {
      const int row = mt * 16 + lmod;
      const int kb = ks * 64 + ldiv * 16;        // byte offset along K
      const int cbs = kb ^ ((row & 7) << 4);
      a[mt] = *(const bf16x8*)((const char*)at + row * 512 + cbs);
    }
#pragma unroll
    for (int nt = 0; nt < 4; ++nt) {
      const int n = wave * 64 + nt * 16 + lmod;
      b[nt] = *(const bf16x8*)&bt[(size_t)n * N_IN_CH + ks * 32 + ldiv * 8];
    }
#pragma unroll
    for (int mt = 0; mt < 4; ++mt)
#pragma unroll
      for (int nt = 0; nt < 4; ++nt)
        acc[mt][nt] = __builtin_amdgcn_mfma_f32_16x16x32_bf16(
            a[mt], b[nt], acc[mt][nt], 0, 0, 0);
  }

  // ---- epilogue: bf16 x_h store + fused logits (wave == head) ----
  float atts[4], attd[4];
#pragma unroll
  for (int nt = 0; nt < 4; ++nt) {
    const int gcol = wave * 64 + nt * 16 + lmod;
    atts[nt] = att_src[gcol];
    attd[nt] = att_dst[gcol];
  }

#pragma unroll
  for (int mt = 0; mt < 4; ++mt) {
#pragma unroll
    for (int reg = 0; reg < 4; ++reg) {
      const int grow = n0 + mt * 16 + ldiv * 4 + reg;  // C/D: row=(lane>>4)*4+reg
      const bool ok = grow < nnodes;
      float vs = 0.f, vd = 0.f;
#pragma unroll
      for (int nt = 0; nt < 4; ++nt) {
        const float v = acc[mt][nt][reg];
        if (ok) xh[(size_t)grow * N_OUT + wave * 64 + nt * 16 + lmod] = f2bf(v);
        vs = fmaf(v, atts[nt], vs);
        vd = fmaf(v, attd[nt], vd);
      }
#pragma unroll
      for (int d = 1; d < 16; d <<= 1) {
        vs += __shfl_xor(vs, d, 64);
        vd += __shfl_xor(vd, d, 64);
      }
      if (lmod == 0 && ok) {
        asrc[grow * HEADS + wave] = vs;
        adst[grow * HEADS + wave] = vd;
      }
    }
  }
}

// ---------------- Kernel B: count edges per destination (row) ----------------
__global__ void count_kernel(const int* __restrict__ row, int* __restrict__ counts,
                             int nedges) {
  int e = blockIdx.x * blockDim.x + threadIdx.x;
  if (e < nedges) atomicAdd(&counts[row[e]], 1);
}

// ---------------- Scan (3 tiny kernels, hierarchical) ----------------
__global__ __launch_bounds__(SCAN_BLOCK) void scan1_kernel(
    const int* __restrict__ counts, int* __restrict__ offsets,
    int* __restrict__ partials, int n) {
  __shared__ int wsum[16];
  const int tid = threadIdx.x;
  const int lane = tid & 63;
  const int wid = tid >> 6;
  const int i = blockIdx.x * SCAN_BLOCK + tid;
  int v = (i < n) ? counts[i] : 0;
  int incl = v;
#pragma unroll
  for (int d = 1; d < 64; d <<= 1) {
    int t = __shfl_up(incl, d, 64);
    if (lane >= d) incl += t;
  }
  if (lane == 63) wsum[wid] = incl;
  __syncthreads();
  if (wid == 0) {
    int wv = (lane < 16) ? wsum[lane] : 0;
#pragma unroll
    for (int d = 1; d < 16; d <<= 1) {
      int t = __shfl_up(wv, d, 64);
      if (lane >= d) wv += t;
    }
    if (lane < 16) wsum[lane] = wv;
  }
  __syncthreads();
  const int wexcl = (wid == 0) ? 0 : wsum[wid - 1];
  if (i < n) offsets[i] = wexcl + incl - v;
  if (tid == SCAN_BLOCK - 1) partials[blockIdx.x] = wsum[15];
}

__global__ void scan2_kernel(int* __restrict__ partials, int* __restrict__ offsets,
                             int nparts, int n) {
  const int lane = threadIdx.x;  // 64 threads, nparts <= 64
  int v = (lane < nparts) ? partials[lane] : 0;
  int incl = v;
#pragma unroll
  for (int d = 1; d < 64; d <<= 1) {
    int t = __shfl_up(incl, d, 64);
    if (lane >= d) incl += t;
  }
  if (lane < nparts) partials[lane] = incl - v;  // exclusive
  if (lane == 63) offsets[n] = incl;             // grand total
}

__global__ __launch_bounds__(SCAN_BLOCK) void scan3_kernel(
    int* __restrict__ offsets, const int* __restrict__ partials, int n) {
  const int i = blockIdx.x * SCAN_BLOCK + threadIdx.x;
  if (i < n) offsets[i] += partials[blockIdx.x];
}

// ---------------- Kernel D: scatter edge ids into CSR ----------------
__global__ void scatter_kernel(const int* __restrict__ row, const int* __restrict__ offsets,
                               int* __restrict__ cursor, int* __restrict__ elist,
                               int nedges) {
  int e = blockIdx.x * blockDim.x + threadIdx.x;
  if (e < nedges) {
    int r = row[e];
    int pos = offsets[r] + atomicAdd(&cursor[r], 1);
    elist[pos] = e;
  }
}

// ---------------- Kernel E: per-node softmax + weighted gather ----------------
__global__ __launch_bounds__(256) void gather_kernel(
    const int* __restrict__ offsets, const int* __restrict__ elist,
    const int* __restrict__ col, const float* __restrict__ asrc,
    const float* __restrict__ adst, const ushort* __restrict__ xh,
    const float* __restrict__ bias, float* __restrict__ out, int nnodes) {
  const int n = blockIdx.x * 4 + (threadIdx.x >> 6);  // one wave per node
  const int lane = threadIdx.x & 63;
  if (n >= nnodes) return;
  const int off = offsets[n];
  const int deg = offsets[n + 1] - off;
  const int h = lane >> 4;  // lane owns channels [4*lane, 4*lane+4) -> head lane>>4

  const float4 as4 = *(const float4*)&asrc[n * 4];

  // phase 1: per-head max over this node's edges
  float m0 = -1e30f, m1 = -1e30f, m2 = -1e30f, m3 = -1e30f;
  for (int i = lane; i < deg; i += 64) {
    const int e = elist[off + i];
    const int cl = col[e];
    const float4 ad = *(const float4*)&adst[cl * 4];
    m0 = fmaxf(m0, lrelu(as4.x + ad.x));
    m1 = fmaxf(m1, lrelu(as4.y + ad.y));
    m2 = fmaxf(m2, lrelu(as4.z + ad.z));
    m3 = fmaxf(m3, lrelu(as4.w + ad.w));
  }
#pragma unroll
  for (int d = 1; d < 64; d <<= 1) {
    m0 = fmaxf(m0, __shfl_xor(m0, d, 64));
    m1 = fmaxf(m1, __shfl_xor(m1, d, 64));
    m2 = fmaxf(m2, __shfl_xor(m2, d, 64));
    m3 = fmaxf(m3, __shfl_xor(m3, d, 64));
  }

  // phase 2: per-head sum of exp(alpha - max)
  float s0 = 0.f, s1 = 0.f, s2 = 0.f, s3 = 0.f;
  for (int i = lane; i < deg; i += 64) {
    const int e = elist[off + i];
    const int cl = col[e];
    const float4 ad = *(const float4*)&adst[cl * 4];
    s0 += __expf(lrelu(as4.x + ad.x) - m0);
    s1 += __expf(lrelu(as4.y + ad.y) - m1);
    s2 += __expf(lrelu(as4.z + ad.z) - m2);
    s3 += __expf(lrelu(as4.w + ad.w) - m3);
  }
#pragma unroll
  for (int d = 1; d < 64; d <<= 1) {
    s0 += __shfl_xor(s0, d, 64);
    s1 += __shfl_xor(s1, d, 64);
    s2 += __shfl_xor(s2, d, 64);
    s3 += __shfl_xor(s3, d, 64);
  }

  const float mh   = (h == 0) ? m0 : (h == 1) ? m1 : (h == 2) ? m2 : m3;
  const float sh   = (h == 0) ? s0 : (h == 1) ? s1 : (h == 2) ? s2 : s3;
  const float ash  = (h == 0) ? as4.x : (h == 1) ? as4.y : (h == 2) ? as4.z : as4.w;
  const float invh = 1.f / fmaxf(sh, 1e-16f);

  // phase 3: weighted gather-accumulate of bf16 x_h[col] rows
  float4 acc = make_float4(0.f, 0.f, 0.f, 0.f);
  for (int i = 0; i < deg; ++i) {
    const int e = elist[off + i];        // wave-uniform
    const int cl = col[e];
    const float ad = adst[cl * 4 + h];
    const float w = __expf(lrelu(ash + ad) - mh) * invh;
    const uint2 xv = *(const uint2*)&xh[(size_t)cl * N_OUT + (lane << 2)];
    acc.x = fmaf(w, __uint_as_float((xv.x & 0xFFFFu) << 16), acc.x);
    acc.y = fmaf(w, __uint_as_float(xv.x & 0xFFFF0000u), acc.y);
    acc.z = fmaf(w, __uint_as_float((xv.y & 0xFFFFu) << 16), acc.z);
    acc.w = fmaf(w, __uint_as_float(xv.y & 0xFFFF0000u), acc.w);
  }

  const float4 b4 = *(const float4*)&bias[lane << 2];
  float4 o = make_float4(acc.x + b4.x, acc.y + b4.y, acc.z + b4.z, acc.w + b4.w);
  *(float4*)&out[(size_t)n * N_OUT + (lane << 2)] = o;
}

extern "C" void kernel_launch(void* const* d_in, const int* in_sizes, int n_in,
                              void* d_out, int out_size, void* d_ws, size_t ws_size,
                              hipStream_t stream) {
  const float* x        = (const float*)d_in[0];
  const int*   edge_idx = (const int*)d_in[1];
  const float* weight   = (const float*)d_in[2];
  const float* att_src  = (const float*)d_in[3];
  const float* att_dst  = (const float*)d_in[4];
  const float* bias     = (const float*)d_in[5];
  float* out = (float*)d_out;

  const int nnodes = in_sizes[0] / N_IN_CH;
  const int nedges = in_sizes[1] / 2;
  const int* row = edge_idx;            // destinations (segment index)
  const int* col = edge_idx + nedges;   // sources (features gathered)

  // workspace carve-up (256B aligned)
  char* wsb = (char*)d_ws;
  size_t woff = 0;
  auto alloc = [&](size_t bytes) -> char* {
    char* p = wsb + woff;
    woff += (bytes + 255) & ~(size_t)255;
    return p;
  };
  ushort* xh    = (ushort*)alloc((size_t)nnodes * N_OUT * sizeof(ushort));
  ushort* bt    = (ushort*)alloc((size_t)N_OUT * N_IN_CH * sizeof(ushort));
  float* asrc   = (float*)alloc((size_t)nnodes * HEADS * sizeof(float));
  float* adst   = (float*)alloc((size_t)nnodes * HEADS * sizeof(float));
  int* counts   = (int*)alloc((size_t)nnodes * sizeof(int));
  int* cursor   = (int*)alloc((size_t)nnodes * sizeof(int));
  int* offsets  = (int*)alloc((size_t)(nnodes + 1) * sizeof(int));
  int* partials = (int*)alloc(256 * sizeof(int));
  int* elist    = (int*)alloc((size_t)nedges * sizeof(int));

  hipMemsetAsync(counts, 0, (size_t)nnodes * sizeof(int), stream);
  hipMemsetAsync(cursor, 0, (size_t)nnodes * sizeof(int), stream);

  convert_w<<<256, 256, 0, stream>>>(weight, bt);

  const int nblocksA = (nnodes + BM - 1) / BM;
  proj_mfma<<<nblocksA, 256, 0, stream>>>(x, bt, att_src, att_dst,
                                          xh, asrc, adst, nnodes);

  const int eblocks = (nedges + 255) / 256;
  count_kernel<<<eblocks, 256, 0, stream>>>(row, counts, nedges);

  const int nscan = (nnodes + SCAN_BLOCK - 1) / SCAN_BLOCK;  // 49 <= 64
  scan1_kernel<<<nscan, SCAN_BLOCK, 0, stream>>>(counts, offsets, partials, nnodes);
  scan2_kernel<<<1, 64, 0, stream>>>(partials, offsets, nscan, nnodes);
  scan3_kernel<<<nscan, SCAN_BLOCK, 0, stream>>>(offsets, partials, nnodes);

  scatter_kernel<<<eblocks, 256, 0, stream>>>(row, offsets, cursor, elist, nedges);

  gather_kernel<<<(nnodes + 3) / 4, 256, 0, stream>>>(offsets, elist, col, asrc, adst,
                                                      xh, bias, out, nnodes);
}

// Round 3
// 202.245 us; speedup vs baseline: 2.1631x; 1.4164x over previous
//
#include <hip/hip_runtime.h>
#include <math.h>

#define N_IN_CH 256
#define N_OUT   256   // HEADS * OUT_CH
#define HEADS   4
#define OUT_CH  64
#define BM      64    // M-tile (nodes) per block in MFMA proj kernel
#define SCAN_BLOCK 1024

typedef __attribute__((ext_vector_type(8))) short bf16x8;
typedef __attribute__((ext_vector_type(4))) float f32x4;

__device__ __forceinline__ float lrelu(float a) {
  return a >= 0.f ? a : 0.2f * a;
}

__device__ __forceinline__ ushort f2bf(float f) {
  uint u = __float_as_uint(f);
  uint r = (u + 0x7FFFu + ((u >> 16) & 1u)) >> 16;
  return (ushort)r;
}

__device__ __forceinline__ float bflo(uint u) {
  return __uint_as_float((u & 0xFFFFu) << 16);
}
__device__ __forceinline__ float bfhi(uint u) {
  return __uint_as_float(u & 0xFFFF0000u);
}

// -------- Kernel W: weight [H][K][C] fp32 -> Bt [N=h*64+c][K] bf16 --------
__global__ void convert_w(const float* __restrict__ w, ushort* __restrict__ bt) {
  const int idx = blockIdx.x * 256 + threadIdx.x;  // 0..65535
  const int n = idx >> 8, k = idx & 255;
  const int h = n >> 6, c = n & 63;
  bt[idx] = f2bf(w[h * (N_IN_CH * OUT_CH) + k * OUT_CH + c]);
}

// -------- Kernel A: x_h = x @ W' via MFMA + fused attention logits --------
__global__ __launch_bounds__(256) void proj_mfma(
    const float* __restrict__ x, const ushort* __restrict__ bt,
    const float* __restrict__ att_src, const float* __restrict__ att_dst,
    ushort* __restrict__ xh, float* __restrict__ asrc, float* __restrict__ adst,
    int nnodes) {
  __shared__ ushort at[BM * N_IN_CH];  // 32 KB, XOR-swizzled rows of A (bf16)
  const int tid = threadIdx.x;
  const int wave = tid >> 6;
  const int lane = tid & 63;
  const int n0 = blockIdx.x * BM;

  // ---- stage A: fp32 -> bf16, swizzled LDS write (conflict-free) ----
  {
    const int rsub = tid >> 6;        // 0..3
    const int cf = (tid & 63) * 4;    // float col
    const int cb = cf * 2;            // byte col
#pragma unroll
    for (int it = 0; it < 16; ++it) {
      const int row = it * 4 + rsub;
      const int grow = n0 + row;
      float4 xv = make_float4(0.f, 0.f, 0.f, 0.f);
      if (grow < nnodes) xv = *(const float4*)&x[(size_t)grow * N_IN_CH + cf];
      ushort4 b;
      b.x = f2bf(xv.x); b.y = f2bf(xv.y); b.z = f2bf(xv.z); b.w = f2bf(xv.w);
      const int cbs = cb ^ ((row & 7) << 4);
      *(ushort4*)((char*)at + row * 512 + cbs) = b;
    }
  }
  __syncthreads();

  f32x4 acc[4][4];
#pragma unroll
  for (int mt = 0; mt < 4; ++mt)
#pragma unroll
    for (int nt = 0; nt < 4; ++nt) acc[mt][nt] = (f32x4){0.f, 0.f, 0.f, 0.f};

  const int lmod = lane & 15;
  const int ldiv = lane >> 4;

  for (int ks = 0; ks < 8; ++ks) {
    bf16x8 a[4], b[4];
#pragma unroll
    for (int mt = 0; mt < 4; ++mt) {
      const int row = mt * 16 + lmod;
      const int kb = ks * 64 + ldiv * 16;
      const int cbs = kb ^ ((row & 7) << 4);
      a[mt] = *(const bf16x8*)((const char*)at + row * 512 + cbs);
    }
#pragma unroll
    for (int nt = 0; nt < 4; ++nt) {
      const int n = wave * 64 + nt * 16 + lmod;
      b[nt] = *(const bf16x8*)&bt[(size_t)n * N_IN_CH + ks * 32 + ldiv * 8];
    }
#pragma unroll
    for (int mt = 0; mt < 4; ++mt)
#pragma unroll
      for (int nt = 0; nt < 4; ++nt)
        acc[mt][nt] = __builtin_amdgcn_mfma_f32_16x16x32_bf16(
            a[mt], b[nt], acc[mt][nt], 0, 0, 0);
  }

  float atts[4], attd[4];
#pragma unroll
  for (int nt = 0; nt < 4; ++nt) {
    const int gcol = wave * 64 + nt * 16 + lmod;
    atts[nt] = att_src[gcol];
    attd[nt] = att_dst[gcol];
  }

#pragma unroll
  for (int mt = 0; mt < 4; ++mt) {
#pragma unroll
    for (int reg = 0; reg < 4; ++reg) {
      const int grow = n0 + mt * 16 + ldiv * 4 + reg;  // C/D: row=(lane>>4)*4+reg
      const bool ok = grow < nnodes;
      float vs = 0.f, vd = 0.f;
#pragma unroll
      for (int nt = 0; nt < 4; ++nt) {
        const float v = acc[mt][nt][reg];
        if (ok) xh[(size_t)grow * N_OUT + wave * 64 + nt * 16 + lmod] = f2bf(v);
        vs = fmaf(v, atts[nt], vs);
        vd = fmaf(v, attd[nt], vd);
      }
#pragma unroll
      for (int d = 1; d < 16; d <<= 1) {
        vs += __shfl_xor(vs, d, 64);
        vd += __shfl_xor(vd, d, 64);
      }
      if (lmod == 0 && ok) {
        asrc[grow * HEADS + wave] = vs;
        adst[grow * HEADS + wave] = vd;
      }
    }
  }
}

// ---------------- Kernel B: count edges per destination ----------------
__global__ void count_kernel(const int* __restrict__ row, int* __restrict__ counts,
                             int nedges) {
  int e = blockIdx.x * blockDim.x + threadIdx.x;
  if (e < nedges) atomicAdd(&counts[row[e]], 1);
}

// ---------------- Scan (3 tiny kernels, hierarchical) ----------------
__global__ __launch_bounds__(SCAN_BLOCK) void scan1_kernel(
    const int* __restrict__ counts, int* __restrict__ offsets,
    int* __restrict__ partials, int n) {
  __shared__ int wsum[16];
  const int tid = threadIdx.x;
  const int lane = tid & 63;
  const int wid = tid >> 6;
  const int i = blockIdx.x * SCAN_BLOCK + tid;
  int v = (i < n) ? counts[i] : 0;
  int incl = v;
#pragma unroll
  for (int d = 1; d < 64; d <<= 1) {
    int t = __shfl_up(incl, d, 64);
    if (lane >= d) incl += t;
  }
  if (lane == 63) wsum[wid] = incl;
  __syncthreads();
  if (wid == 0) {
    int wv = (lane < 16) ? wsum[lane] : 0;
#pragma unroll
    for (int d = 1; d < 16; d <<= 1) {
      int t = __shfl_up(wv, d, 64);
      if (lane >= d) wv += t;
    }
    if (lane < 16) wsum[lane] = wv;
  }
  __syncthreads();
  const int wexcl = (wid == 0) ? 0 : wsum[wid - 1];
  if (i < n) offsets[i] = wexcl + incl - v;
  if (tid == SCAN_BLOCK - 1) partials[blockIdx.x] = wsum[15];
}

__global__ void scan2_kernel(int* __restrict__ partials, int* __restrict__ offsets,
                             int nparts, int n) {
  const int lane = threadIdx.x;
  int v = (lane < nparts) ? partials[lane] : 0;
  int incl = v;
#pragma unroll
  for (int d = 1; d < 64; d <<= 1) {
    int t = __shfl_up(incl, d, 64);
    if (lane >= d) incl += t;
  }
  if (lane < nparts) partials[lane] = incl - v;
  if (lane == 63) offsets[n] = incl;
}

// scan3 also seeds cursor = offsets (saves a memset + lets scatter emit
// absolute positions in one atomic)
__global__ __launch_bounds__(SCAN_BLOCK) void scan3_kernel(
    int* __restrict__ offsets, const int* __restrict__ partials,
    int* __restrict__ cursor, int n) {
  const int i = blockIdx.x * SCAN_BLOCK + threadIdx.x;
  if (i < n) {
    const int v = offsets[i] + partials[blockIdx.x];
    offsets[i] = v;
    cursor[i] = v;
  }
}

// ---------------- Kernel D: scatter col values into CSR order ----------------
__global__ void scatter_kernel(const int* __restrict__ row, const int* __restrict__ col,
                               int* __restrict__ cursor, int* __restrict__ ccol,
                               int nedges) {
  int e = blockIdx.x * blockDim.x + threadIdx.x;
  if (e < nedges) {
    int pos = atomicAdd(&cursor[row[e]], 1);
    ccol[pos] = col[e];
  }
}

// ---------------- Kernel E: per-node softmax + weighted gather ----------------
// One wave per node. Phase 1: lane-parallel max. Phase 2+3 fused per 64-edge
// chunk: lanes compute unnormalized p (all heads) -> LDS; wave then streams the
// chunk's xh rows 4-at-a-time (deep MLP). Normalize once at the end.
__global__ __launch_bounds__(256) void gather_kernel(
    const int* __restrict__ offsets, const int* __restrict__ ccol,
    const float* __restrict__ asrc, const float* __restrict__ adst,
    const ushort* __restrict__ xh, const float* __restrict__ bias,
    float* __restrict__ out, int nnodes) {
  __shared__ float pbuf[4][64 * 4];
  __shared__ int clbuf[4][64];
  const int wv = threadIdx.x >> 6;
  const int lane = threadIdx.x & 63;
  const int n = blockIdx.x * 4 + wv;
  if (n >= nnodes) return;
  const int off = offsets[n];
  const int deg = offsets[n + 1] - off;
  const int h = lane >> 4;
  const int xoff = lane << 2;

  const float4 as4 = *(const float4*)&asrc[n * 4];

  // phase 1: per-head max (lane-parallel)
  float m0 = -1e30f, m1 = -1e30f, m2 = -1e30f, m3 = -1e30f;
  for (int i = lane; i < deg; i += 64) {
    const int cl = ccol[off + i];
    const float4 ad = *(const float4*)&adst[cl * 4];
    m0 = fmaxf(m0, lrelu(as4.x + ad.x));
    m1 = fmaxf(m1, lrelu(as4.y + ad.y));
    m2 = fmaxf(m2, lrelu(as4.z + ad.z));
    m3 = fmaxf(m3, lrelu(as4.w + ad.w));
  }
#pragma unroll
  for (int d = 1; d < 64; d <<= 1) {
    m0 = fmaxf(m0, __shfl_xor(m0, d, 64));
    m1 = fmaxf(m1, __shfl_xor(m1, d, 64));
    m2 = fmaxf(m2, __shfl_xor(m2, d, 64));
    m3 = fmaxf(m3, __shfl_xor(m3, d, 64));
  }

  // phase 2+3 fused
  float s0 = 0.f, s1 = 0.f, s2 = 0.f, s3 = 0.f;
  float4 acc = make_float4(0.f, 0.f, 0.f, 0.f);

  for (int b = 0; b < deg; b += 64) {
    const int cnt = min(64, deg - b);
    float4 p = make_float4(0.f, 0.f, 0.f, 0.f);
    int cl_l = 0;
    if (lane < cnt) {
      cl_l = ccol[off + b + lane];
      const float4 ad = *(const float4*)&adst[cl_l * 4];
      p.x = __expf(lrelu(as4.x + ad.x) - m0);
      p.y = __expf(lrelu(as4.y + ad.y) - m1);
      p.z = __expf(lrelu(as4.z + ad.z) - m2);
      p.w = __expf(lrelu(as4.w + ad.w) - m3);
      s0 += p.x; s1 += p.y; s2 += p.z; s3 += p.w;
    }
    *(float4*)&pbuf[wv][lane * 4] = p;
    clbuf[wv][lane] = cl_l;
    // same-wave LDS write->read: hardware-ordered via lgkmcnt (no barrier)

    int j = 0;
    for (; j + 4 <= cnt; j += 4) {
      const int c0 = clbuf[wv][j + 0];
      const int c1 = clbuf[wv][j + 1];
      const int c2 = clbuf[wv][j + 2];
      const int c3 = clbuf[wv][j + 3];
      const uint2 x0 = *(const uint2*)&xh[(size_t)c0 * N_OUT + xoff];
      const uint2 x1 = *(const uint2*)&xh[(size_t)c1 * N_OUT + xoff];
      const uint2 x2 = *(const uint2*)&xh[(size_t)c2 * N_OUT + xoff];
      const uint2 x3 = *(const uint2*)&xh[(size_t)c3 * N_OUT + xoff];
      const float w0 = pbuf[wv][(j + 0) * 4 + h];
      const float w1 = pbuf[wv][(j + 1) * 4 + h];
      const float w2 = pbuf[wv][(j + 2) * 4 + h];
      const float w3 = pbuf[wv][(j + 3) * 4 + h];
      acc.x = fmaf(w0, bflo(x0.x), acc.x);
      acc.y = fmaf(w0, bfhi(x0.x), acc.y);
      acc.z = fmaf(w0, bflo(x0.y), acc.z);
      acc.w = fmaf(w0, bfhi(x0.y), acc.w);
      acc.x = fmaf(w1, bflo(x1.x), acc.x);
      acc.y = fmaf(w1, bfhi(x1.x), acc.y);
      acc.z = fmaf(w1, bflo(x1.y), acc.z);
      acc.w = fmaf(w1, bfhi(x1.y), acc.w);
      acc.x = fmaf(w2, bflo(x2.x), acc.x);
      acc.y = fmaf(w2, bfhi(x2.x), acc.y);
      acc.z = fmaf(w2, bflo(x2.y), acc.z);
      acc.w = fmaf(w2, bfhi(x2.y), acc.w);
      acc.x = fmaf(w3, bflo(x3.x), acc.x);
      acc.y = fmaf(w3, bfhi(x3.x), acc.y);
      acc.z = fmaf(w3, bflo(x3.y), acc.z);
      acc.w = fmaf(w3, bfhi(x3.y), acc.w);
    }
    for (; j < cnt; ++j) {
      const int c0 = clbuf[wv][j];
      const uint2 x0 = *(const uint2*)&xh[(size_t)c0 * N_OUT + xoff];
      const float w0 = pbuf[wv][j * 4 + h];
      acc.x = fmaf(w0, bflo(x0.x), acc.x);
      acc.y = fmaf(w0, bfhi(x0.x), acc.y);
      acc.z = fmaf(w0, bflo(x0.y), acc.z);
      acc.w = fmaf(w0, bfhi(x0.y), acc.w);
    }
  }

#pragma unroll
  for (int d = 1; d < 64; d <<= 1) {
    s0 += __shfl_xor(s0, d, 64);
    s1 += __shfl_xor(s1, d, 64);
    s2 += __shfl_xor(s2, d, 64);
    s3 += __shfl_xor(s3, d, 64);
  }
  const float sh = (h == 0) ? s0 : (h == 1) ? s1 : (h == 2) ? s2 : s3;
  const float invh = 1.f / fmaxf(sh, 1e-16f);

  const float4 b4 = *(const float4*)&bias[xoff];
  float4 o;
  o.x = fmaf(acc.x, invh, b4.x);
  o.y = fmaf(acc.y, invh, b4.y);
  o.z = fmaf(acc.z, invh, b4.z);
  o.w = fmaf(acc.w, invh, b4.w);
  *(float4*)&out[(size_t)n * N_OUT + xoff] = o;
}

extern "C" void kernel_launch(void* const* d_in, const int* in_sizes, int n_in,
                              void* d_out, int out_size, void* d_ws, size_t ws_size,
                              hipStream_t stream) {
  const float* x        = (const float*)d_in[0];
  const int*   edge_idx = (const int*)d_in[1];
  const float* weight   = (const float*)d_in[2];
  const float* att_src  = (const float*)d_in[3];
  const float* att_dst  = (const float*)d_in[4];
  const float* bias     = (const float*)d_in[5];
  float* out = (float*)d_out;

  const int nnodes = in_sizes[0] / N_IN_CH;
  const int nedges = in_sizes[1] / 2;
  const int* row = edge_idx;            // destinations (segment index)
  const int* col = edge_idx + nedges;   // sources (features gathered)

  char* wsb = (char*)d_ws;
  size_t woff = 0;
  auto alloc = [&](size_t bytes) -> char* {
    char* p = wsb + woff;
    woff += (bytes + 255) & ~(size_t)255;
    return p;
  };
  ushort* xh    = (ushort*)alloc((size_t)nnodes * N_OUT * sizeof(ushort));
  ushort* bt    = (ushort*)alloc((size_t)N_OUT * N_IN_CH * sizeof(ushort));
  float* asrc   = (float*)alloc((size_t)nnodes * HEADS * sizeof(float));
  float* adst   = (float*)alloc((size_t)nnodes * HEADS * sizeof(float));
  int* counts   = (int*)alloc((size_t)nnodes * sizeof(int));
  int* cursor   = (int*)alloc((size_t)nnodes * sizeof(int));
  int* offsets  = (int*)alloc((size_t)(nnodes + 1) * sizeof(int));
  int* partials = (int*)alloc(256 * sizeof(int));
  int* ccol     = (int*)alloc((size_t)nedges * sizeof(int));

  hipMemsetAsync(counts, 0, (size_t)nnodes * sizeof(int), stream);

  convert_w<<<256, 256, 0, stream>>>(weight, bt);

  const int nblocksA = (nnodes + BM - 1) / BM;
  proj_mfma<<<nblocksA, 256, 0, stream>>>(x, bt, att_src, att_dst,
                                          xh, asrc, adst, nnodes);

  const int eblocks = (nedges + 255) / 256;
  count_kernel<<<eblocks, 256, 0, stream>>>(row, counts, nedges);

  const int nscan = (nnodes + SCAN_BLOCK - 1) / SCAN_BLOCK;
  scan1_kernel<<<nscan, SCAN_BLOCK, 0, stream>>>(counts, offsets, partials, nnodes);
  scan2_kernel<<<1, 64, 0, stream>>>(partials, offsets, nscan, nnodes);
  scan3_kernel<<<nscan, SCAN_BLOCK, 0, stream>>>(offsets, partials, cursor, nnodes);

  scatter_kernel<<<eblocks, 256, 0, stream>>>(row, col, cursor, ccol, nedges);

  gather_kernel<<<(nnodes + 3) / 4, 256, 0, stream>>>(offsets, ccol, asrc, adst,
                                                      xh, bias, out, nnodes);
}

// Round 4
// 181.004 us; speedup vs baseline: 2.4169x; 1.1174x over previous
//
#include <hip/hip_runtime.h>
#include <math.h>

#define N_IN_CH 256
#define N_OUT   256   // HEADS * OUT_CH
#define HEADS   4
#define OUT_CH  64
#define BM      64    // M-tile (nodes) per block in MFMA proj kernel
#define SCAN_BLOCK 1024

typedef __attribute__((ext_vector_type(8))) short bf16x8;
typedef __attribute__((ext_vector_type(4))) float f32x4;

__device__ __forceinline__ float lrelu(float a) {
  return a >= 0.f ? a : 0.2f * a;
}

__device__ __forceinline__ ushort f2bf(float f) {
  uint u = __float_as_uint(f);
  uint r = (u + 0x7FFFu + ((u >> 16) & 1u)) >> 16;
  return (ushort)r;
}

__device__ __forceinline__ float bflo(uint u) {
  return __uint_as_float((u & 0xFFFFu) << 16);
}
__device__ __forceinline__ float bfhi(uint u) {
  return __uint_as_float(u & 0xFFFF0000u);
}

// -------- Kernel W: weight [H][K][C] fp32 -> Bt [N][K] bf16; zero counts ----
__global__ void convert_w(const float* __restrict__ w, ushort* __restrict__ bt,
                          int* __restrict__ counts, int nnodes) {
  const int idx = blockIdx.x * 256 + threadIdx.x;  // 0..65535
  if (idx < nnodes) counts[idx] = 0;
  const int n = idx >> 8, k = idx & 255;
  const int h = n >> 6, c = n & 63;
  bt[idx] = f2bf(w[h * (N_IN_CH * OUT_CH) + k * OUT_CH + c]);
}

// -------- Kernel A: x_h = x @ W' via MFMA + logits + fused edge count ------
__global__ __launch_bounds__(256) void proj_mfma(
    const float* __restrict__ x, const ushort* __restrict__ bt,
    const float* __restrict__ att_src, const float* __restrict__ att_dst,
    ushort* __restrict__ xh, float* __restrict__ asrc, float* __restrict__ adst,
    int nnodes, const int* __restrict__ row, int* __restrict__ counts,
    int* __restrict__ rank, int nedges) {
  __shared__ ushort at[BM * N_IN_CH];  // 32 KB, XOR-swizzled rows of A (bf16)
  const int tid = threadIdx.x;
  const int wave = tid >> 6;
  const int lane = tid & 63;
  const int n0 = blockIdx.x * BM;

  // ---- stage A: fp32 -> bf16, swizzled LDS write (conflict-free) ----
  {
    const int rsub = tid >> 6;
    const int cf = (tid & 63) * 4;
    const int cb = cf * 2;
#pragma unroll
    for (int it = 0; it < 16; ++it) {
      const int row_ = it * 4 + rsub;
      const int grow = n0 + row_;
      float4 xv = make_float4(0.f, 0.f, 0.f, 0.f);
      if (grow < nnodes) xv = *(const float4*)&x[(size_t)grow * N_IN_CH + cf];
      ushort4 b;
      b.x = f2bf(xv.x); b.y = f2bf(xv.y); b.z = f2bf(xv.z); b.w = f2bf(xv.w);
      const int cbs = cb ^ ((row_ & 7) << 4);
      *(ushort4*)((char*)at + row_ * 512 + cbs) = b;
    }
  }
  __syncthreads();

  f32x4 acc[4][4];
#pragma unroll
  for (int mt = 0; mt < 4; ++mt)
#pragma unroll
    for (int nt = 0; nt < 4; ++nt) acc[mt][nt] = (f32x4){0.f, 0.f, 0.f, 0.f};

  const int lmod = lane & 15;
  const int ldiv = lane >> 4;

  for (int ks = 0; ks < 8; ++ks) {
    bf16x8 a[4], b[4];
#pragma unroll
    for (int mt = 0; mt < 4; ++mt) {
      const int row_ = mt * 16 + lmod;
      const int kb = ks * 64 + ldiv * 16;
      const int cbs = kb ^ ((row_ & 7) << 4);
      a[mt] = *(const bf16x8*)((const char*)at + row_ * 512 + cbs);
    }
#pragma unroll
    for (int nt = 0; nt < 4; ++nt) {
      const int n = wave * 64 + nt * 16 + lmod;
      b[nt] = *(const bf16x8*)&bt[(size_t)n * N_IN_CH + ks * 32 + ldiv * 8];
    }
#pragma unroll
    for (int mt = 0; mt < 4; ++mt)
#pragma unroll
      for (int nt = 0; nt < 4; ++nt)
        acc[mt][nt] = __builtin_amdgcn_mfma_f32_16x16x32_bf16(
            a[mt], b[nt], acc[mt][nt], 0, 0, 0);
  }

  float atts[4], attd[4];
#pragma unroll
  for (int nt = 0; nt < 4; ++nt) {
    const int gcol = wave * 64 + nt * 16 + lmod;
    atts[nt] = att_src[gcol];
    attd[nt] = att_dst[gcol];
  }

#pragma unroll
  for (int mt = 0; mt < 4; ++mt) {
#pragma unroll
    for (int reg = 0; reg < 4; ++reg) {
      const int grow = n0 + mt * 16 + ldiv * 4 + reg;  // C/D: row=(lane>>4)*4+reg
      const bool ok = grow < nnodes;
      float vs = 0.f, vd = 0.f;
#pragma unroll
      for (int nt = 0; nt < 4; ++nt) {
        const float v = acc[mt][nt][reg];
        if (ok) xh[(size_t)grow * N_OUT + wave * 64 + nt * 16 + lmod] = f2bf(v);
        vs = fmaf(v, atts[nt], vs);
        vd = fmaf(v, attd[nt], vd);
      }
#pragma unroll
      for (int d = 1; d < 16; d <<= 1) {
        vs += __shfl_xor(vs, d, 64);
        vd += __shfl_xor(vd, d, 64);
      }
      if (lmod == 0 && ok) {
        asrc[grow * HEADS + wave] = vs;
        adst[grow * HEADS + wave] = vd;
      }
    }
  }

  // ---- fused edge count + rank (overlaps with other blocks' MFMA) ----
  const int gtid = blockIdx.x * 256 + tid;
  const int stride = gridDim.x * 256;
  for (int e = gtid; e < nedges; e += stride) {
    rank[e] = atomicAdd(&counts[row[e]], 1);
  }
}

// ---------------- scan1: block-local exclusive scan over n+1 elems ----------
__global__ __launch_bounds__(SCAN_BLOCK) void scan1_kernel(
    const int* __restrict__ counts, int* __restrict__ offsets,
    int* __restrict__ partials, int n) {
  __shared__ int wsum[16];
  const int tid = threadIdx.x;
  const int lane = tid & 63;
  const int wid = tid >> 6;
  const int i = blockIdx.x * SCAN_BLOCK + tid;
  int v = (i < n) ? counts[i] : 0;
  int incl = v;
#pragma unroll
  for (int d = 1; d < 64; d <<= 1) {
    int t = __shfl_up(incl, d, 64);
    if (lane >= d) incl += t;
  }
  if (lane == 63) wsum[wid] = incl;
  __syncthreads();
  if (wid == 0) {
    int wv = (lane < 16) ? wsum[lane] : 0;
#pragma unroll
    for (int d = 1; d < 16; d <<= 1) {
      int t = __shfl_up(wv, d, 64);
      if (lane >= d) wv += t;
    }
    if (lane < 16) wsum[lane] = wv;
  }
  __syncthreads();
  const int wexcl = (wid == 0) ? 0 : wsum[wid - 1];
  if (i <= n) offsets[i] = wexcl + incl - v;
  if (tid == SCAN_BLOCK - 1) partials[blockIdx.x] = wsum[15];
}

// ---------------- scan2: exclusive scan of the 49 block sums ----------------
__global__ void scan2_kernel(int* __restrict__ partials, int nparts) {
  const int lane = threadIdx.x;  // 64 threads
  int v = (lane < nparts) ? partials[lane] : 0;
  int incl = v;
#pragma unroll
  for (int d = 1; d < 64; d <<= 1) {
    int t = __shfl_up(incl, d, 64);
    if (lane >= d) incl += t;
  }
  if (lane < nparts) partials[lane] = incl - v;
}

// ------------- scatter (atomic-free): ccol[pos] = col[e] --------------------
__global__ void scatter_kernel(const int* __restrict__ row, const int* __restrict__ col,
                               const int* __restrict__ rank,
                               const int* __restrict__ offsets,
                               const int* __restrict__ partials,
                               int* __restrict__ ccol, int nedges) {
  int e = blockIdx.x * blockDim.x + threadIdx.x;
  if (e < nedges) {
    const int r = row[e];
    const int pos = offsets[r] + partials[r >> 10] + rank[e];
    ccol[pos] = col[e];
  }
}

// ---------------- gather: online softmax + deep-MLP weighted gather ---------
__global__ __launch_bounds__(256) void gather_kernel(
    const int* __restrict__ offsets, const int* __restrict__ partials,
    const int* __restrict__ ccol,
    const float* __restrict__ asrc, const float* __restrict__ adst,
    const ushort* __restrict__ xh, const float* __restrict__ bias,
    float* __restrict__ out, int nnodes) {
  __shared__ float pbuf[4][64 * 4];
  __shared__ int clbuf[4][64];
  const int wv = threadIdx.x >> 6;
  const int lane = threadIdx.x & 63;
  const int n = blockIdx.x * 4 + wv;
  if (n >= nnodes) return;
  const int off = offsets[n] + partials[n >> 10];
  const int end = offsets[n + 1] + partials[(n + 1) >> 10];
  const int deg = end - off;
  const int h = lane >> 4;
  const int xoff = lane << 2;

  const float4 as4 = *(const float4*)&asrc[n * 4];

  float m0 = -1e30f, m1 = -1e30f, m2 = -1e30f, m3 = -1e30f;
  float s0 = 0.f, s1 = 0.f, s2 = 0.f, s3 = 0.f;
  float4 acc = make_float4(0.f, 0.f, 0.f, 0.f);

  for (int b = 0; b < deg; b += 64) {
    const int cnt = min(64, deg - b);
    float a0 = -1e30f, a1 = -1e30f, a2 = -1e30f, a3 = -1e30f;
    int cl_l = 0;
    if (lane < cnt) {
      cl_l = ccol[off + b + lane];
      const float4 ad = *(const float4*)&adst[cl_l * 4];
      a0 = lrelu(as4.x + ad.x);
      a1 = lrelu(as4.y + ad.y);
      a2 = lrelu(as4.z + ad.z);
      a3 = lrelu(as4.w + ad.w);
    }
    // chunk max per head
    float c0 = a0, c1 = a1, c2 = a2, c3 = a3;
#pragma unroll
    for (int d = 1; d < 64; d <<= 1) {
      c0 = fmaxf(c0, __shfl_xor(c0, d, 64));
      c1 = fmaxf(c1, __shfl_xor(c1, d, 64));
      c2 = fmaxf(c2, __shfl_xor(c2, d, 64));
      c3 = fmaxf(c3, __shfl_xor(c3, d, 64));
    }
    const float nm0 = fmaxf(m0, c0), nm1 = fmaxf(m1, c1);
    const float nm2 = fmaxf(m2, c2), nm3 = fmaxf(m3, c3);
    const float sc0 = __expf(m0 - nm0), sc1 = __expf(m1 - nm1);
    const float sc2 = __expf(m2 - nm2), sc3 = __expf(m3 - nm3);
    m0 = nm0; m1 = nm1; m2 = nm2; m3 = nm3;
    float4 p;
    p.x = __expf(a0 - m0);
    p.y = __expf(a1 - m1);
    p.z = __expf(a2 - m2);
    p.w = __expf(a3 - m3);
    s0 = s0 * sc0 + p.x;
    s1 = s1 * sc1 + p.y;
    s2 = s2 * sc2 + p.z;
    s3 = s3 * sc3 + p.w;
    const float sch = (h == 0) ? sc0 : (h == 1) ? sc1 : (h == 2) ? sc2 : sc3;
    acc.x *= sch; acc.y *= sch; acc.z *= sch; acc.w *= sch;

    *(float4*)&pbuf[wv][lane * 4] = p;
    clbuf[wv][lane] = cl_l;
    // same-wave LDS write->read: hardware-ordered via lgkmcnt (no barrier)

    int j = 0;
    for (; j + 8 <= cnt; j += 8) {
      int c[8];
      uint2 xr[8];
      float w[8];
#pragma unroll
      for (int q = 0; q < 8; ++q) c[q] = clbuf[wv][j + q];
#pragma unroll
      for (int q = 0; q < 8; ++q)
        xr[q] = *(const uint2*)&xh[(size_t)c[q] * N_OUT + xoff];
#pragma unroll
      for (int q = 0; q < 8; ++q) w[q] = pbuf[wv][(j + q) * 4 + h];
#pragma unroll
      for (int q = 0; q < 8; ++q) {
        acc.x = fmaf(w[q], bflo(xr[q].x), acc.x);
        acc.y = fmaf(w[q], bfhi(xr[q].x), acc.y);
        acc.z = fmaf(w[q], bflo(xr[q].y), acc.z);
        acc.w = fmaf(w[q], bfhi(xr[q].y), acc.w);
      }
    }
    for (; j < cnt; ++j) {
      const int c0_ = clbuf[wv][j];
      const uint2 x0 = *(const uint2*)&xh[(size_t)c0_ * N_OUT + xoff];
      const float w0 = pbuf[wv][j * 4 + h];
      acc.x = fmaf(w0, bflo(x0.x), acc.x);
      acc.y = fmaf(w0, bfhi(x0.x), acc.y);
      acc.z = fmaf(w0, bflo(x0.y), acc.z);
      acc.w = fmaf(w0, bfhi(x0.y), acc.w);
    }
  }

#pragma unroll
  for (int d = 1; d < 64; d <<= 1) {
    s0 += __shfl_xor(s0, d, 64);
    s1 += __shfl_xor(s1, d, 64);
    s2 += __shfl_xor(s2, d, 64);
    s3 += __shfl_xor(s3, d, 64);
  }
  const float sh = (h == 0) ? s0 : (h == 1) ? s1 : (h == 2) ? s2 : s3;
  const float invh = 1.f / fmaxf(sh, 1e-16f);

  const float4 b4 = *(const float4*)&bias[xoff];
  float4 o;
  o.x = fmaf(acc.x, invh, b4.x);
  o.y = fmaf(acc.y, invh, b4.y);
  o.z = fmaf(acc.z, invh, b4.z);
  o.w = fmaf(acc.w, invh, b4.w);
  *(float4*)&out[(size_t)n * N_OUT + xoff] = o;
}

extern "C" void kernel_launch(void* const* d_in, const int* in_sizes, int n_in,
                              void* d_out, int out_size, void* d_ws, size_t ws_size,
                              hipStream_t stream) {
  const float* x        = (const float*)d_in[0];
  const int*   edge_idx = (const int*)d_in[1];
  const float* weight   = (const float*)d_in[2];
  const float* att_src  = (const float*)d_in[3];
  const float* att_dst  = (const float*)d_in[4];
  const float* bias     = (const float*)d_in[5];
  float* out = (float*)d_out;

  const int nnodes = in_sizes[0] / N_IN_CH;
  const int nedges = in_sizes[1] / 2;
  const int* row = edge_idx;            // destinations (segment index)
  const int* col = edge_idx + nedges;   // sources (features gathered)

  char* wsb = (char*)d_ws;
  size_t woff = 0;
  auto alloc = [&](size_t bytes) -> char* {
    char* p = wsb + woff;
    woff += (bytes + 255) & ~(size_t)255;
    return p;
  };
  ushort* xh    = (ushort*)alloc((size_t)nnodes * N_OUT * sizeof(ushort));
  ushort* bt    = (ushort*)alloc((size_t)N_OUT * N_IN_CH * sizeof(ushort));
  float* asrc   = (float*)alloc((size_t)nnodes * HEADS * sizeof(float));
  float* adst   = (float*)alloc((size_t)nnodes * HEADS * sizeof(float));
  int* counts   = (int*)alloc((size_t)nnodes * sizeof(int));
  int* offsets  = (int*)alloc((size_t)(nnodes + 1) * sizeof(int));
  int* partials = (int*)alloc(256 * sizeof(int));
  int* rank     = (int*)alloc((size_t)nedges * sizeof(int));
  int* ccol     = (int*)alloc((size_t)nedges * sizeof(int));

  convert_w<<<256, 256, 0, stream>>>(weight, bt, counts, nnodes);

  const int nblocksA = (nnodes + BM - 1) / BM;
  proj_mfma<<<nblocksA, 256, 0, stream>>>(x, bt, att_src, att_dst,
                                          xh, asrc, adst, nnodes,
                                          row, counts, rank, nedges);

  const int nscan = (nnodes + 1 + SCAN_BLOCK - 1) / SCAN_BLOCK;  // 49
  scan1_kernel<<<nscan, SCAN_BLOCK, 0, stream>>>(counts, offsets, partials, nnodes);
  scan2_kernel<<<1, 64, 0, stream>>>(partials, nscan);

  const int eblocks = (nedges + 255) / 256;
  scatter_kernel<<<eblocks, 256, 0, stream>>>(row, col, rank, offsets, partials,
                                              ccol, nedges);

  gather_kernel<<<(nnodes + 3) / 4, 256, 0, stream>>>(offsets, partials, ccol,
                                                      asrc, adst, xh, bias, out,
                                                      nnodes);
}